// Round 1
// baseline (316.315 us; speedup 1.0000x reference)
//
#include <hip/hip_runtime.h>
#include <stdint.h>

#define N_CAND 25200
#define NB 16
#define ROW 85
#define TK 1024
#define MAXDET 300
#define CAP 2048
#define BITS_LO 0x3E800000u

// ---------------- Kernel 1: per-candidate score/class, one wave per candidate ----------------
__global__ __launch_bounds__(256) void score_kernel(
    const float* __restrict__ pred,
    unsigned long long* __restrict__ keys,
    unsigned char* __restrict__ cls8)
{
#pragma clang fp contract(off)
    const int lane = threadIdx.x & 63;
    const long long w = ((long long)blockIdx.x * blockDim.x + threadIdx.x) >> 6;
    if (w >= (long long)NB * N_CAND) return;
    const float* row = pred + w * ROW;

    float v0 = row[lane];                                   // elements 0..63
    float v1 = (lane < ROW - 64) ? row[64 + lane] : 0.0f;   // elements 64..84
    float obj = __shfl(v0, 4, 64);

    // class products, exactly like reference: conf_all = obj * cls, argmax first-occurrence
    float p0 = (lane >= 5) ? obj * v0 : -3.402823466e+38f;  // class idx lane-5 (0..58)
    int   i0 = lane - 5;
    float p1 = (lane < 21) ? obj * v1 : -3.402823466e+38f;  // class idx 59+lane (59..79)
    int   i1 = 59 + lane;

    float bv; int bi;
    if (p1 > p0) { bv = p1; bi = i1; } else { bv = p0; bi = i0; }  // tie -> lower idx

    // wave argmax reduce (butterfly); tie -> lower class index
    for (int off = 32; off > 0; off >>= 1) {
        float ov = __shfl_xor(bv, off, 64);
        int   oi = __shfl_xor(bi, off, 64);
        if (ov > bv || (ov == bv && oi < bi)) { bv = ov; bi = oi; }
    }

    if (lane == 0) {
        float conf = bv;
        bool valid = (obj > 0.25f) && (conf > 0.25f);
        unsigned int n = (unsigned int)(w % N_CAND);
        unsigned long long key = 0ull;
        if (valid)
            key = ((unsigned long long)__float_as_uint(conf) << 32) | (unsigned int)(~n);
        keys[w] = key;
        cls8[w] = (unsigned char)bi;
    }
}

// ---------------- Kernel 2: per-batch top-k + sort + sequential NMS + output ----------------
__global__ __launch_bounds__(1024) void nms_kernel(
    const float* __restrict__ pred,
    const unsigned long long* __restrict__ keys,
    const unsigned char* __restrict__ cls8,
    float* __restrict__ out)
{
#pragma clang fp contract(off)
    __shared__ unsigned long long sbuf[CAP];          // 16 KB
    __shared__ unsigned int hist[2048];               // 8 KB
    __shared__ float ssc[TK], rx1[TK], ry1[TK], rx2[TK], ry2[TK], clsf[TK], area[TK]; // 28 KB
    __shared__ int sup[TK];                           // 4 KB
    __shared__ int sel[MAXDET];
    __shared__ unsigned int s_thr;
    __shared__ int s_cnt, s_p, s_ptr, s_nsel;

    const int tid = threadIdx.x;
    const int b = blockIdx.x;
    const unsigned long long* kb = keys + (size_t)b * N_CAND;
    const unsigned char* cb = cls8 + (size_t)b * N_CAND;
    const float* pb = pred + (size_t)b * N_CAND * ROW;

    // Phase A: histogram of conf bits (valid conf in (0.25, 1.0) -> bins 0..2047)
    for (int i = tid; i < 2048; i += 1024) hist[i] = 0;
    if (tid == 0) s_cnt = 0;
    __syncthreads();
    for (int n = tid; n < N_CAND; n += 1024) {
        unsigned int bits = (unsigned int)(kb[n] >> 32);
        if (bits) {
            int bin = (int)((bits - BITS_LO) >> 13);
            bin = bin < 0 ? 0 : (bin > 2047 ? 2047 : bin);
            atomicAdd(&hist[bin], 1u);
        }
    }
    __syncthreads();
    if (tid == 0) {
        unsigned int acc = 0; int t = 0;
        for (int bin = 2047; bin >= 0; --bin) {
            acc += hist[bin];
            if (acc >= TK) { t = bin; break; }
        }
        s_thr = BITS_LO + ((unsigned int)t << 13);
    }
    __syncthreads();
    const unsigned int thr = s_thr;

    // Phase B: gather all candidates at/above threshold bin
    for (int n = tid; n < N_CAND; n += 1024) {
        unsigned long long k = kb[n];
        if ((unsigned int)(k >> 32) >= thr) {
            int pos = atomicAdd(&s_cnt, 1);
            if (pos < CAP) sbuf[pos] = k;
        }
    }
    __syncthreads();
    int cnt = s_cnt; if (cnt > CAP) cnt = CAP;
    for (int i = tid; i < CAP; i += 1024) if (i >= cnt) sbuf[i] = 0ull;
    __syncthreads();

    // Phase C: bitonic sort ascending (descending view read from the top)
    for (int k = 2; k <= CAP; k <<= 1) {
        for (int j = k >> 1; j > 0; j >>= 1) {
            for (int i = tid; i < CAP; i += 1024) {
                int ixj = i ^ j;
                if (ixj > i) {
                    unsigned long long a = sbuf[i], c = sbuf[ixj];
                    bool up = ((i & k) == 0);
                    if (up ? (a > c) : (a < c)) { sbuf[i] = c; sbuf[ixj] = a; }
                }
            }
            __syncthreads();
        }
    }

    // Phase D: extract top-1024 (slot 0 = best) + gather boxes
    {
        const int i = tid;
        unsigned long long k = sbuf[CAP - 1 - i];
        unsigned int bits = (unsigned int)(k >> 32);
        if (bits) {
            unsigned int n = ~((unsigned int)k);
            const float* r = pb + (size_t)n * ROW;
            float x = r[0], y = r[1], ww = r[2], hh = r[3];
            float hw = ww * 0.5f, hv = hh * 0.5f;
            float a1 = x - hw, b1 = y - hv, a2 = x + hw, b2 = y + hv;
            float c = (float)cb[n];
            float offc = c * 4096.0f;
            ssc[i] = __uint_as_float(bits);
            rx1[i] = a1; ry1[i] = b1; rx2[i] = a2; ry2[i] = b2;
            clsf[i] = c;
            // areas from OFFSET coords, exactly like reference
            area[i] = ((a2 + offc) - (a1 + offc)) * ((b2 + offc) - (b1 + offc));
        } else {
            ssc[i] = -1.0f;
            rx1[i] = ry1[i] = rx2[i] = ry2[i] = 0.0f;
            clsf[i] = 0.0f; area[i] = 0.0f;
        }
        sup[i] = 0;
    }
    if (tid == 0) { s_ptr = 0; s_nsel = 0; }
    __syncthreads();

    // Phase E: greedy sequential NMS (argmax over sorted-desc == first unsuppressed)
    for (int it = 0; it < MAXDET; ++it) {
        if (tid == 0) {
            int ptr = s_ptr;
            while (ptr < TK && (sup[ptr] != 0 || !(ssc[ptr] > 0.0f))) ++ptr;
            s_ptr = ptr;
            if (ptr < TK) { s_p = ptr; sel[it] = ptr; s_nsel = it + 1; }
            else s_p = -1;
        }
        __syncthreads();
        const int p = s_p;
        if (p < 0) break;
        {
            const int j = tid;
            float offp = clsf[p] * 4096.0f;
            float px1 = rx1[p] + offp, py1 = ry1[p] + offp;
            float px2 = rx2[p] + offp, py2 = ry2[p] + offp;
            float offj = clsf[j] * 4096.0f;
            float qx1 = rx1[j] + offj, qy1 = ry1[j] + offj;
            float qx2 = rx2[j] + offj, qy2 = ry2[j] + offj;
            float ltx = fmaxf(px1, qx1), lty = fmaxf(py1, qy1);
            float rbx = fminf(px2, qx2), rby = fminf(py2, qy2);
            float w2 = fmaxf(rbx - ltx, 0.0f), h2 = fmaxf(rby - lty, 0.0f);
            float inter = w2 * h2;
            float denom = area[p] + area[j] - inter + 1e-9f;
            float iou = inter / denom;
            if (iou > 0.45f) sup[j] = 1;
        }
        __syncthreads();
    }

    // Epilogue: write 300 rows (scale_coords: gain=0.5, pad=(0,140); zeros stay zeros)
    const int nsel = s_nsel;
    for (int r = tid; r < MAXDET; r += 1024) {
        float* o = out + ((size_t)b * MAXDET + r) * 6;
        if (r < nsel) {
            int p = sel[r];
            float X1 = (rx1[p] - 0.0f) / 0.5f;
            float Y1 = (ry1[p] - 140.0f) / 0.5f;
            float X2 = (rx2[p] - 0.0f) / 0.5f;
            float Y2 = (ry2[p] - 140.0f) / 0.5f;
            X1 = fminf(fmaxf(X1, 0.0f), 1280.0f);
            Y1 = fminf(fmaxf(Y1, 0.0f), 720.0f);
            X2 = fminf(fmaxf(X2, 0.0f), 1280.0f);
            Y2 = fminf(fmaxf(Y2, 0.0f), 720.0f);
            o[0] = X1; o[1] = Y1; o[2] = X2; o[3] = Y2;
            o[4] = ssc[p]; o[5] = clsf[p];
        } else {
            o[0] = 0.0f; o[1] = 0.0f; o[2] = 0.0f;
            o[3] = 0.0f; o[4] = 0.0f; o[5] = 0.0f;
        }
    }
}

extern "C" void kernel_launch(void* const* d_in, const int* in_sizes, int n_in,
                              void* d_out, int out_size, void* d_ws, size_t ws_size,
                              hipStream_t stream)
{
    const float* pred = (const float*)d_in[0];
    float* out = (float*)d_out;
    unsigned long long* keys = (unsigned long long*)d_ws;
    unsigned char* cls8 = (unsigned char*)((char*)d_ws + (size_t)NB * N_CAND * sizeof(unsigned long long));

    const int totalThreads = NB * N_CAND * 64;         // one wave per candidate
    const int blocks = (totalThreads + 255) / 256;     // 100800
    score_kernel<<<blocks, 256, 0, stream>>>(pred, keys, cls8);
    nms_kernel<<<NB, 1024, 0, stream>>>(pred, keys, cls8, out);
}

// Round 2
// 148.359 us; speedup vs baseline: 2.1321x; 2.1321x over previous
//
#include <hip/hip_runtime.h>
#include <stdint.h>

#define N_CAND 25200
#define NB 16
#define ROW 85
#define TK 1024
#define MAXDET 300
#define CAP 2048
#define BITS_LO 0x3E800000u

typedef unsigned long long u64;
typedef unsigned int u32;

// ---------------- K1: score + key, thread-per-row via LDS staging ----------------
__global__ __launch_bounds__(64) void score_kernel(const float* __restrict__ pred,
                                                   u64* __restrict__ keys)
{
#pragma clang fp contract(off)
    __shared__ float tile[64 * ROW];                 // 21.76 KB
    const int tid = threadIdx.x;
    const int row0 = blockIdx.x * 64;                // 6300 blocks exactly
    // cooperative coalesced load: 64 rows * 85 floats = 1360 float4 (16B-aligned base)
    const float4* src = (const float4*)(pred + (size_t)row0 * ROW);
    float4* dst = (float4*)tile;
    for (int i = tid; i < (64 * ROW) / 4; i += 64) dst[i] = src[i];
    __syncthreads();

    const float* r = tile + tid * ROW;               // stride 85: gcd(85,32)=1 -> conflict-free
    float obj = r[4];
    float best = obj * r[5];
    int bi = 0;
    for (int c = 1; c < 80; ++c) {
        float p = obj * r[5 + c];
        if (p > best) { best = p; bi = c; }          // strict > : first-occurrence argmax
    }
    int w = row0 + tid;
    u32 n = (u32)(w % N_CAND);
    u64 key = 0;
    if (obj > 0.25f && best > 0.25f)
        key = ((u64)__float_as_uint(best) << 32) | (((u64)(25199u - n)) << 7) | (u32)bi;
    keys[w] = key;                                   // desc sort => conf desc, n asc (ties)
}

// ---------------- K2: per-batch histogram + parallel suffix-sum + gather + bitonic sort -> SoA ----------------
__global__ __launch_bounds__(1024) void topk_kernel(const float* __restrict__ pred,
                                                    const u64* __restrict__ keys,
                                                    float4* __restrict__ soaA,
                                                    float4* __restrict__ soaB)
{
#pragma clang fp contract(off)
    __shared__ u64 sbuf[CAP];                        // 16 KB
    __shared__ u32 histA[2048];                      // 8 KB
    __shared__ u32 histB[2048];                      // 8 KB
    __shared__ u32 s_t;
    __shared__ int s_cnt;

    const int tid = threadIdx.x;
    const int b = blockIdx.x;
    const u64* kb = keys + (size_t)b * N_CAND;
    const float* pb = pred + (size_t)b * N_CAND * ROW;

    for (int i = tid; i < 2048; i += 1024) histA[i] = 0;
    if (tid == 0) { s_cnt = 0; s_t = 0; }
    __syncthreads();

    // Phase A: histogram of conf bits
    for (int n = tid; n < N_CAND; n += 1024) {
        u32 bits = (u32)(kb[n] >> 32);
        if (bits) {
            int bin = (int)((bits - BITS_LO) >> 13);
            bin = bin < 0 ? 0 : (bin > 2047 ? 2047 : bin);
            atomicAdd(&histA[bin], 1u);
        }
    }
    __syncthreads();

    // Phase A2: parallel suffix sum (Hillis-Steele, 11 passes)
    u32* srcp = histA; u32* dstp = histB;
    for (int step = 1; step < 2048; step <<= 1) {
        for (int i = tid; i < 2048; i += 1024)
            dstp[i] = srcp[i] + ((i + step < 2048) ? srcp[i + step] : 0u);
        __syncthreads();
        u32* t = srcp; srcp = dstp; dstp = t;
    }
    // largest bin t with suffix >= TK (matches serial top-down scan)
    for (int i = tid; i < 2048; i += 1024) {
        u32 S = srcp[i];
        if (S >= TK && (i == 2047 || srcp[i + 1] < TK)) s_t = (u32)i;
    }
    __syncthreads();
    const u32 thr = BITS_LO + (s_t << 13);

    // Phase B: gather candidates >= threshold bin
    for (int n = tid; n < N_CAND; n += 1024) {
        u64 k = kb[n];
        if ((u32)(k >> 32) >= thr) {
            int pos = atomicAdd(&s_cnt, 1);
            if (pos < CAP) sbuf[pos] = k;
        }
    }
    __syncthreads();
    int cnt = s_cnt; if (cnt > CAP) cnt = CAP;
    for (int i = tid; i < CAP; i += 1024) if (i >= cnt) sbuf[i] = 0ull;
    __syncthreads();

    // Phase C: bitonic sort ascending (read desc from the top)
    for (int k = 2; k <= CAP; k <<= 1) {
        for (int j = k >> 1; j > 0; j >>= 1) {
            for (int i = tid; i < CAP; i += 1024) {
                int ixj = i ^ j;
                if (ixj > i) {
                    u64 a = sbuf[i], c = sbuf[ixj];
                    bool up = ((i & k) == 0);
                    if (up ? (a > c) : (a < c)) { sbuf[i] = c; sbuf[ixj] = a; }
                }
            }
            __syncthreads();
        }
    }

    // Phase D: extract top-1024, gather boxes, write SoA planes
    {
        const int i = tid;
        u64 k = sbuf[CAP - 1 - i];
        u32 bits = (u32)(k >> 32);
        float4 A, Bv;
        if (bits) {
            u32 lo = (u32)k;
            u32 n = 25199u - (lo >> 7);
            float c = (float)(lo & 127u);
            const float* rp = pb + (size_t)n * ROW;
            float x = rp[0], y = rp[1], ww = rp[2], hh = rp[3];
            float hw = ww * 0.5f, hv = hh * 0.5f;
            float x1 = x - hw, y1 = y - hv, x2 = x + hw, y2 = y + hv;
            float offc = c * 4096.0f;
            float area = ((x2 + offc) - (x1 + offc)) * ((y2 + offc) - (y1 + offc));
            A = make_float4(x1, y1, x2, y2);
            Bv = make_float4(area, __uint_as_float(bits), c, 0.0f);
        } else {
            A = make_float4(0.0f, 0.0f, 0.0f, 0.0f);
            Bv = make_float4(0.0f, -1.0f, 0.0f, 0.0f);
        }
        soaA[b * TK + i] = A;
        soaB[b * TK + i] = Bv;
    }
}

// ---------------- K3: 1024x1024 suppression bitmask matrix (whole-GPU parallel) ----------------
__global__ __launch_bounds__(512) void mask_kernel(const float4* __restrict__ soaA,
                                                   const float4* __restrict__ soaB,
                                                   u64* __restrict__ masks)
{
#pragma clang fp contract(off)
    __shared__ float4 cA[TK];                        // 16 KB
    __shared__ float4 cB[TK];                        // 16 KB
    const int tid = threadIdx.x;
    const int b = blockIdx.y;
    const int rbase = blockIdx.x * 64;
    for (int i = tid; i < TK; i += 512) { cA[i] = soaA[b * TK + i]; cB[i] = soaB[b * TK + i]; }
    __syncthreads();

    const int wave = tid >> 6, lane = tid & 63;
    for (int rr = 0; rr < 8; ++rr) {
        int i = rbase + (wave << 3) + rr;
        float4 P = cA[i]; float4 Pb = cB[i];         // broadcast reads
        float offp = Pb.z * 4096.0f;
        float px1 = P.x + offp, py1 = P.y + offp, px2 = P.z + offp, py2 = P.w + offp;
        float parea = Pb.x;
        u64 myword = 0;
        for (int word = 0; word < 16; ++word) {
            int j = (word << 6) + lane;
            float4 Q = cA[j]; float4 Qb = cB[j];     // stride-16B: conflict-free b128
            float offj = Qb.z * 4096.0f;
            float qx1 = Q.x + offj, qy1 = Q.y + offj, qx2 = Q.z + offj, qy2 = Q.w + offj;
            float ltx = fmaxf(px1, qx1), lty = fmaxf(py1, qy1);
            float rbx = fminf(px2, qx2), rby = fminf(py2, qy2);
            float w2 = fmaxf(rbx - ltx, 0.0f), h2 = fmaxf(rby - lty, 0.0f);
            float inter = w2 * h2;
            float iou = inter / (parea + Qb.x - inter + 1e-9f);
            u64 m = __ballot(iou > 0.45f);
            if (lane == word) myword = m;
        }
        if (lane < 16) masks[((size_t)(b * TK + i) << 4) + lane] = myword;  // coalesced 128B
    }
}

// ---------------- K4: per-batch single-wave greedy sweep + output ----------------
__global__ __launch_bounds__(64) void sweep_kernel(const float4* __restrict__ soaA,
                                                   const float4* __restrict__ soaB,
                                                   const u64* __restrict__ masks,
                                                   float* __restrict__ out)
{
#pragma clang fp contract(off)
    __shared__ int sel[MAXDET];
    const int lane = threadIdx.x;
    const int b = blockIdx.x;
    const u64* mb = masks + ((size_t)(b * TK) << 4);

    // count of positive scores (sorted desc -> contiguous prefix)
    int nv = TK;
    for (int k = 0; k < 16; ++k) {
        float s = soaB[b * TK + (k << 6) + lane].y;
        u64 m = __ballot(s > 0.0f);
        if (m != ~0ull) { nv = (k << 6) + (int)__builtin_ctzll(~m); break; }
    }

    u64 removed = 0;                                 // lane w (w<16) owns word w
    int nsel = 0;
    bool done = (nv == 0);
    const int li = lane & 15;

    u64 cur[8], nxt[8];
#pragma unroll
    for (int r = 0; r < 8; ++r) cur[r] = mb[((size_t)r << 4) + li];

    for (int c = 0; c < 128 && !done; ++c) {
        int nb0 = (c + 1) << 3;
#pragma unroll
        for (int r = 0; r < 8; ++r) {                // prefetch next chunk
            int i2 = nb0 + r; if (i2 > TK - 1) i2 = TK - 1;
            nxt[r] = mb[((size_t)i2 << 4) + li];
        }
#pragma unroll
        for (int r = 0; r < 8; ++r) {
            int i = (c << 3) + r;
            if (!done && i < nv) {
                u64 wv = __shfl(removed, i >> 6, 64);
                if (!((wv >> (i & 63)) & 1ull)) {    // alive -> select
                    if (lane == 0) sel[nsel] = i;
                    removed |= cur[r];
                    ++nsel;
                    if (nsel == MAXDET) done = true;
                }
            } else if (i >= nv) done = true;
        }
#pragma unroll
        for (int r = 0; r < 8; ++r) cur[r] = nxt[r];
    }
    __syncthreads();

    // epilogue: scale_coords (gain=0.5, pad=(0,140)) + write 300 rows
    for (int r = lane; r < MAXDET; r += 64) {
        float* o = out + ((size_t)b * MAXDET + r) * 6;
        if (r < nsel) {
            int p = sel[r];
            float4 A = soaA[b * TK + p];
            float4 Bv = soaB[b * TK + p];
            float X1 = (A.x - 0.0f) / 0.5f;
            float Y1 = (A.y - 140.0f) / 0.5f;
            float X2 = (A.z - 0.0f) / 0.5f;
            float Y2 = (A.w - 140.0f) / 0.5f;
            X1 = fminf(fmaxf(X1, 0.0f), 1280.0f);
            Y1 = fminf(fmaxf(Y1, 0.0f), 720.0f);
            X2 = fminf(fmaxf(X2, 0.0f), 1280.0f);
            Y2 = fminf(fmaxf(Y2, 0.0f), 720.0f);
            o[0] = X1; o[1] = Y1; o[2] = X2; o[3] = Y2;
            o[4] = Bv.y; o[5] = Bv.z;
        } else {
            o[0] = 0.0f; o[1] = 0.0f; o[2] = 0.0f;
            o[3] = 0.0f; o[4] = 0.0f; o[5] = 0.0f;
        }
    }
}

extern "C" void kernel_launch(void* const* d_in, const int* in_sizes, int n_in,
                              void* d_out, int out_size, void* d_ws, size_t ws_size,
                              hipStream_t stream)
{
    const float* pred = (const float*)d_in[0];
    float* out = (float*)d_out;

    // workspace layout (high-water 3.75 MB):
    //   [0, 3,225,600)          keys (u64 x 403200)  -- dead after K2
    //   [0, 2,097,152)          masks (u64 x 262144) -- aliases keys, written by K3 after K2
    //   [3,225,600, +262,144)   soaA (float4 x 16384)
    //   [3,487,744, +262,144)   soaB (float4 x 16384)
    u64* keys = (u64*)d_ws;
    u64* masks = (u64*)d_ws;
    float4* soaA = (float4*)((char*)d_ws + 3225600);
    float4* soaB = (float4*)((char*)d_ws + 3225600 + 262144);

    score_kernel<<<(NB * N_CAND) / 64, 64, 0, stream>>>(pred, keys);
    topk_kernel<<<NB, 1024, 0, stream>>>(pred, keys, soaA, soaB);
    mask_kernel<<<dim3(16, NB), 512, 0, stream>>>(soaA, soaB, masks);
    sweep_kernel<<<NB, 64, 0, stream>>>(soaA, soaB, masks, out);
}

// Round 3
// 120.386 us; speedup vs baseline: 2.6275x; 1.2324x over previous
//
#include <hip/hip_runtime.h>
#include <stdint.h>

#define N_CAND 25200
#define NB 16
#define ROW 85
#define TK 1024
#define MAXDET 300
#define CAP 2048
#define BITS_LO 0x3E800000u

typedef unsigned long long u64;
typedef unsigned int u32;

static __device__ __forceinline__ u64 u64min(u64 a, u64 b) { return a < b ? a : b; }
static __device__ __forceinline__ u64 u64max(u64 a, u64 b) { return a > b ? a : b; }

// ---------------- K1: score + key, 4 threads per row, 64 rows per 256-thread block ----------------
__global__ __launch_bounds__(256) void score_kernel(const float* __restrict__ pred,
                                                    u64* __restrict__ keys)
{
#pragma clang fp contract(off)
    __shared__ float tile[64 * ROW];                 // 21.76 KB -> 7 blocks/CU, 28 waves/CU
    const int tid = threadIdx.x;
    const int row0 = blockIdx.x * 64;                // 6300 blocks
    // cooperative coalesced load: 1360 float4 (base is 16B-aligned: 64*85*4 = 21760)
    const float4* src = (const float4*)(pred + (size_t)row0 * ROW);
    float4* dst = (float4*)tile;
#pragma unroll
    for (int i = 0; i < 6; ++i) {
        int idx = tid + (i << 8);
        if (idx < (64 * ROW) / 4) dst[idx] = src[idx];
    }
    __syncthreads();

    const int r = tid >> 2, sub = tid & 3;
    const float* rowp = tile + r * ROW;
    const float obj = rowp[4];                       // 4-lane same-address -> broadcast
    const int base = 5 + sub * 20;
    float bv = obj * rowp[base];                     // products, exactly like reference
    int bi = base - 5;
#pragma unroll
    for (int c = 1; c < 20; ++c) {
        float p = obj * rowp[base + c];
        if (p > bv) { bv = p; bi = base - 5 + c; }   // strict > : first occurrence
    }
    // merge across the 4 sub-lanes (xor 1,2 stays inside the 4-group); tie -> lower class idx
#pragma unroll
    for (int off = 1; off <= 2; off <<= 1) {
        float ov = __shfl_xor(bv, off, 64);
        int   oi = __shfl_xor(bi, off, 64);
        if (ov > bv || (ov == bv && oi < bi)) { bv = ov; bi = oi; }
    }
    if (sub == 0) {
        int w = row0 + r;
        u32 n = (u32)(w % N_CAND);
        u64 key = 0;
        if (obj > 0.25f && bv > 0.25f)
            key = ((u64)__float_as_uint(bv) << 32) | (((u64)(25199u - n)) << 7) | (u32)bi;
        keys[w] = key;                               // desc sort => conf desc, n asc (ties)
    }
}

// ---------------- K2: per-batch histogram + suffix-sum + gather + hybrid bitonic sort -> SoA ----------------
__global__ __launch_bounds__(1024) void topk_kernel(const float* __restrict__ pred,
                                                    const u64* __restrict__ keys,
                                                    float4* __restrict__ soaA,
                                                    float4* __restrict__ soaB)
{
#pragma clang fp contract(off)
    __shared__ u64 sbuf[CAP];                        // 16 KB
    __shared__ u32 histA[2048];                      // 8 KB
    __shared__ u32 histB[2048];                      // 8 KB
    __shared__ u32 s_t;
    __shared__ int s_cnt;

    const int tid = threadIdx.x;
    const int b = blockIdx.x;
    const u64* kb = keys + (size_t)b * N_CAND;
    const float* pb = pred + (size_t)b * N_CAND * ROW;

    for (int i = tid; i < 2048; i += 1024) histA[i] = 0;
    if (tid == 0) { s_cnt = 0; s_t = 0; }
    __syncthreads();

    // Phase A: histogram of conf bits (valid conf in (0.25,1) -> bins 0..2047)
    for (int n = tid; n < N_CAND; n += 1024) {
        u32 bits = (u32)(kb[n] >> 32);
        if (bits) {
            int bin = (int)((bits - BITS_LO) >> 13);
            bin = bin < 0 ? 0 : (bin > 2047 ? 2047 : bin);
            atomicAdd(&histA[bin], 1u);
        }
    }
    __syncthreads();

    // Phase A2: parallel suffix sum (Hillis-Steele, 11 passes)
    u32* srcp = histA; u32* dstp = histB;
    for (int step = 1; step < 2048; step <<= 1) {
        for (int i = tid; i < 2048; i += 1024)
            dstp[i] = srcp[i] + ((i + step < 2048) ? srcp[i + step] : 0u);
        __syncthreads();
        u32* t = srcp; srcp = dstp; dstp = t;
    }
    for (int i = tid; i < 2048; i += 1024) {
        u32 S = srcp[i];
        if (S >= TK && (i == 2047 || srcp[i + 1] < TK)) s_t = (u32)i;
    }
    __syncthreads();
    const u32 thr = BITS_LO + (s_t << 13);

    // Phase B: gather candidates >= threshold bin (order-free: sort is value-deterministic)
    for (int n = tid; n < N_CAND; n += 1024) {
        u64 k = kb[n];
        if ((u32)(k >> 32) >= thr) {
            int pos = atomicAdd(&s_cnt, 1);
            if (pos < CAP) sbuf[pos] = k;
        }
    }
    __syncthreads();
    int cnt = s_cnt; if (cnt > CAP) cnt = CAP;
    for (int i = tid; i < CAP; i += 1024) if (i >= cnt) sbuf[i] = 0ull;
    __syncthreads();

    // Phase C: hybrid bitonic sort ascending, 2 elems/thread.
    // j>=128: LDS stage (cross-wave). j in [2,64]: __shfl_xor(j>>1). j==1: in-thread.
    {
        const int E0 = tid << 1;                     // even; E1 = E0+1
        u64 e0 = sbuf[E0], e1 = sbuf[E0 + 1];
        for (int k = 2; k <= CAP; k <<= 1) {
            for (int j = k >> 1; j > 0; j >>= 1) {
                const bool asc = ((E0 & k) == 0);    // same for E1 (k>=2)
                if (j >= 128) {
                    __syncthreads();                 // protect prior reads
                    sbuf[E0] = e0; sbuf[E0 + 1] = e1;
                    __syncthreads();
                    u64 p0 = sbuf[E0 ^ j], p1 = sbuf[(E0 + 1) ^ j];
                    const bool low = ((E0 & j) == 0);  // same for E1 (j>=2)
                    e0 = (asc == low) ? u64min(e0, p0) : u64max(e0, p0);
                    e1 = (asc == low) ? u64min(e1, p1) : u64max(e1, p1);
                } else if (j >= 2) {
                    const int l = j >> 1;
                    u64 p0 = __shfl_xor(e0, l, 64);
                    u64 p1 = __shfl_xor(e1, l, 64);
                    const bool low = ((E0 & j) == 0);
                    e0 = (asc == low) ? u64min(e0, p0) : u64max(e0, p0);
                    e1 = (asc == low) ? u64min(e1, p1) : u64max(e1, p1);
                } else {
                    u64 mn = u64min(e0, e1), mx = u64max(e0, e1);
                    e0 = asc ? mn : mx;
                    e1 = asc ? mx : mn;
                }
            }
        }
        __syncthreads();
        sbuf[E0] = e0; sbuf[E0 + 1] = e1;
        __syncthreads();
    }

    // Phase D: extract top-1024 (slot 0 = best), gather boxes, write SoA
    {
        const int i = tid;
        u64 k = sbuf[CAP - 1 - i];
        u32 bits = (u32)(k >> 32);
        float4 A, Bv;
        if (bits) {
            u32 lo = (u32)k;
            u32 n = 25199u - (lo >> 7);
            float c = (float)(lo & 127u);
            const float* rp = pb + (size_t)n * ROW;
            float x = rp[0], y = rp[1], ww = rp[2], hh = rp[3];
            float hw = ww * 0.5f, hv = hh * 0.5f;
            float x1 = x - hw, y1 = y - hv, x2 = x + hw, y2 = y + hv;
            float offc = c * 4096.0f;
            float area = ((x2 + offc) - (x1 + offc)) * ((y2 + offc) - (y1 + offc));
            A = make_float4(x1, y1, x2, y2);
            Bv = make_float4(area, __uint_as_float(bits), c, 0.0f);
        } else {
            A = make_float4(0.0f, 0.0f, 0.0f, 0.0f);
            Bv = make_float4(0.0f, -1.0f, 0.0f, 0.0f);
        }
        soaA[b * TK + i] = A;
        soaB[b * TK + i] = Bv;
    }
}

// ---------------- K3: 1024x1024 suppression bitmask matrix (whole-GPU parallel) ----------------
__global__ __launch_bounds__(512) void mask_kernel(const float4* __restrict__ soaA,
                                                   const float4* __restrict__ soaB,
                                                   u64* __restrict__ masks)
{
#pragma clang fp contract(off)
    __shared__ float4 cA[TK];                        // 16 KB
    __shared__ float4 cB[TK];                        // 16 KB
    const int tid = threadIdx.x;
    const int b = blockIdx.y;
    const int rbase = blockIdx.x * 64;
    for (int i = tid; i < TK; i += 512) { cA[i] = soaA[b * TK + i]; cB[i] = soaB[b * TK + i]; }
    __syncthreads();

    const int wave = tid >> 6, lane = tid & 63;
    for (int rr = 0; rr < 8; ++rr) {
        int i = rbase + (wave << 3) + rr;
        float4 P = cA[i]; float4 Pb = cB[i];         // broadcast reads
        float offp = Pb.z * 4096.0f;
        float px1 = P.x + offp, py1 = P.y + offp, px2 = P.z + offp, py2 = P.w + offp;
        float parea = Pb.x;
        u64 myword = 0;
        for (int word = 0; word < 16; ++word) {
            int j = (word << 6) + lane;
            float4 Q = cA[j]; float4 Qb = cB[j];
            float offj = Qb.z * 4096.0f;
            float qx1 = Q.x + offj, qy1 = Q.y + offj, qx2 = Q.z + offj, qy2 = Q.w + offj;
            float ltx = fmaxf(px1, qx1), lty = fmaxf(py1, qy1);
            float rbx = fminf(px2, qx2), rby = fminf(py2, qy2);
            float w2 = fmaxf(rbx - ltx, 0.0f), h2 = fmaxf(rby - lty, 0.0f);
            float inter = w2 * h2;
            float iou = inter / (parea + Qb.x - inter + 1e-9f);
            u64 m = __ballot(iou > 0.45f);
            if (lane == word) myword = m;
        }
        if (lane < 16) masks[((size_t)(b * TK + i) << 4) + lane] = myword;  // coalesced 128B
    }
}

// ---------------- K4: per-batch single-wave greedy sweep + output ----------------
__global__ __launch_bounds__(64) void sweep_kernel(const float4* __restrict__ soaA,
                                                   const float4* __restrict__ soaB,
                                                   const u64* __restrict__ masks,
                                                   float* __restrict__ out)
{
#pragma clang fp contract(off)
    __shared__ int sel[MAXDET];
    const int lane = threadIdx.x;
    const int b = blockIdx.x;
    const u64* mb = masks + ((size_t)(b * TK) << 4);

    // count of positive scores (sorted desc -> contiguous prefix)
    int nv = TK;
    for (int k = 0; k < 16; ++k) {
        float s = soaB[b * TK + (k << 6) + lane].y;
        u64 m = __ballot(s > 0.0f);
        if (m != ~0ull) { nv = (k << 6) + (int)__builtin_ctzll(~m); break; }
    }

    u64 removed = 0;                                 // lane w (w<16) owns word w
    int nsel = 0;
    bool done = (nv == 0);
    const int li = lane & 15;

    u64 cur[8], nxt[8];
#pragma unroll
    for (int r = 0; r < 8; ++r) cur[r] = mb[((size_t)r << 4) + li];

    for (int c = 0; c < 128 && !done; ++c) {
        int nb0 = (c + 1) << 3;
#pragma unroll
        for (int r = 0; r < 8; ++r) {                // prefetch next chunk
            int i2 = nb0 + r; if (i2 > TK - 1) i2 = TK - 1;
            nxt[r] = mb[((size_t)i2 << 4) + li];
        }
#pragma unroll
        for (int r = 0; r < 8; ++r) {
            int i = (c << 3) + r;
            if (!done && i < nv) {
                u64 wv = __shfl(removed, i >> 6, 64);
                if (!((wv >> (i & 63)) & 1ull)) {    // alive -> select
                    if (lane == 0) sel[nsel] = i;
                    removed |= cur[r];
                    ++nsel;
                    if (nsel == MAXDET) done = true;
                }
            } else if (i >= nv) done = true;
        }
#pragma unroll
        for (int r = 0; r < 8; ++r) cur[r] = nxt[r];
    }
    __syncthreads();

    // epilogue: scale_coords (gain=0.5, pad=(0,140)) + write 300 rows
    for (int r = lane; r < MAXDET; r += 64) {
        float* o = out + ((size_t)b * MAXDET + r) * 6;
        if (r < nsel) {
            int p = sel[r];
            float4 A = soaA[b * TK + p];
            float4 Bv = soaB[b * TK + p];
            float X1 = (A.x - 0.0f) / 0.5f;
            float Y1 = (A.y - 140.0f) / 0.5f;
            float X2 = (A.z - 0.0f) / 0.5f;
            float Y2 = (A.w - 140.0f) / 0.5f;
            X1 = fminf(fmaxf(X1, 0.0f), 1280.0f);
            Y1 = fminf(fmaxf(Y1, 0.0f), 720.0f);
            X2 = fminf(fmaxf(X2, 0.0f), 1280.0f);
            Y2 = fminf(fmaxf(Y2, 0.0f), 720.0f);
            o[0] = X1; o[1] = Y1; o[2] = X2; o[3] = Y2;
            o[4] = Bv.y; o[5] = Bv.z;
        } else {
            o[0] = 0.0f; o[1] = 0.0f; o[2] = 0.0f;
            o[3] = 0.0f; o[4] = 0.0f; o[5] = 0.0f;
        }
    }
}

extern "C" void kernel_launch(void* const* d_in, const int* in_sizes, int n_in,
                              void* d_out, int out_size, void* d_ws, size_t ws_size,
                              hipStream_t stream)
{
    const float* pred = (const float*)d_in[0];
    float* out = (float*)d_out;

    // workspace layout (high-water 3.75 MB):
    //   [0, 3,225,600)          keys (u64 x 403200)  -- dead after K2
    //   [0, 2,097,152)          masks (u64 x 262144) -- aliases keys, written by K3 after K2
    //   [3,225,600, +262,144)   soaA (float4 x 16384)
    //   [3,487,744, +262,144)   soaB (float4 x 16384)
    u64* keys = (u64*)d_ws;
    u64* masks = (u64*)d_ws;
    float4* soaA = (float4*)((char*)d_ws + 3225600);
    float4* soaB = (float4*)((char*)d_ws + 3225600 + 262144);

    score_kernel<<<(NB * N_CAND) / 64, 256, 0, stream>>>(pred, keys);
    topk_kernel<<<NB, 1024, 0, stream>>>(pred, keys, soaA, soaB);
    mask_kernel<<<dim3(16, NB), 512, 0, stream>>>(soaA, soaB, masks);
    sweep_kernel<<<NB, 64, 0, stream>>>(soaA, soaB, masks, out);
}